// Round 1
// baseline (355.974 us; speedup 1.0000x reference)
//
#include <hip/hip_runtime.h>

// Problem constants (from reference): B=16, S=4096, H=768, NUM_WORDS=2048.
constexpr int B = 16;
constexpr int S = 4096;
constexpr int H = 768;
constexpr int NW = 2048;
constexpr int VEC_PER_ROW = H / 4; // 192 float4 per token row

// One block per (b, word). word_ids[b, 1..S-2] is non-decreasing, so the
// tokens of word w form a contiguous range found by binary search. s=0 and
// s=S-1 are -1 sentinels (excluded from the search range entirely).
__global__ __launch_bounds__(VEC_PER_ROW)
void seg_mean_kernel(const float* __restrict__ hs,
                     const int* __restrict__ wid,
                     float* __restrict__ out) {
    const int blk = blockIdx.x;      // b * NW + w
    const int b = blk >> 11;         // / 2048
    const int w = blk & (NW - 1);

    const int* __restrict__ row = wid + (size_t)b * S;

    // lower_bound of w in row[1 .. S-1)
    int l = 1, r = S - 1;
    while (l < r) {
        int m = (l + r) >> 1;
        if (row[m] < w) l = m + 1; else r = m;
    }
    const int start = l;
    // upper_bound of w in row[start .. S-1)
    r = S - 1;
    while (l < r) {
        int m = (l + r) >> 1;
        if (row[m] <= w) l = m + 1; else r = m;
    }
    const int end = l;
    const int cnt = end - start;

    const int t = threadIdx.x; // one float4 column per thread
    const float4* __restrict__ base =
        (const float4*)(hs + (size_t)b * S * H);

    float4 acc = make_float4(0.f, 0.f, 0.f, 0.f);
    for (int s = start; s < end; ++s) {
        float4 v = base[(size_t)s * VEC_PER_ROW + t];
        acc.x += v.x; acc.y += v.y; acc.z += v.z; acc.w += v.w;
    }

    const float inv = (cnt > 0) ? (1.0f / (float)cnt) : 0.0f;
    acc.x *= inv; acc.y *= inv; acc.z *= inv; acc.w *= inv;

    float4* __restrict__ o = (float4*)(out + (size_t)blk * H);
    o[t] = acc;
}

extern "C" void kernel_launch(void* const* d_in, const int* in_sizes, int n_in,
                              void* d_out, int out_size, void* d_ws, size_t ws_size,
                              hipStream_t stream) {
    const float* hs = (const float*)d_in[0];
    const int* wid = (const int*)d_in[1];
    float* out = (float*)d_out;

    dim3 grid(B * NW);
    dim3 block(VEC_PER_ROW);
    seg_mean_kernel<<<grid, block, 0, stream>>>(hs, wid, out);
}

// Round 2
// 342.479 us; speedup vs baseline: 1.0394x; 1.0394x over previous
//
#include <hip/hip_runtime.h>

// Problem constants (from reference): B=16, S=4096, H=768, NUM_WORDS=2048.
constexpr int B = 16;
constexpr int S = 4096;
constexpr int H = 768;
constexpr int NW = 2048;
constexpr int VEC_PER_ROW = H / 4; // 192 float4 per token row

// Phase 1: word_ids[b, 1..S-2] is non-decreasing with increments of 0/1
// (cumsum of bernoulli), sentinels -1 at s=0 and s=S-1. Position s starts
// word row[s] iff row[s] != row[s-1]. Scatter the start index of each
// existing word into starts[b*NW + w]. Entries for non-existent words
// (w > row[S-2]) are never written and never read.
__global__ __launch_bounds__(256)
void find_starts_kernel(const int* __restrict__ wid, int* __restrict__ starts) {
    const int idx = blockIdx.x * 256 + threadIdx.x; // over B*S
    const int s = idx & (S - 1);
    const int b = idx >> 12;
    if (s < 1 || s >= S - 1) return;
    const int* __restrict__ row = wid + (size_t)b * S;
    const int cur = row[s];
    const int prev = row[s - 1];
    if (cur != prev && cur >= 0) {
        starts[b * NW + cur] = s;
    }
}

// Phase 2: one block per (b, word). Tokens of word w are the contiguous
// range [starts[w], starts[w+1]) (end = S-1 for the last existing word).
__global__ __launch_bounds__(VEC_PER_ROW)
void seg_mean_kernel(const float* __restrict__ hs,
                     const int* __restrict__ wid,
                     const int* __restrict__ starts,
                     float* __restrict__ out) {
    const int blk = blockIdx.x;      // b * NW + w
    const int b = blk >> 11;         // / 2048
    const int w = blk & (NW - 1);
    const int t = threadIdx.x;       // one float4 column per thread

    float4* __restrict__ o = (float4*)(out + (size_t)blk * H);

    // Highest existing word id in this row (interior last token).
    const int maxw = wid[(size_t)b * S + (S - 2)];

    if (w > maxw) {
        o[t] = make_float4(0.f, 0.f, 0.f, 0.f);
        return;
    }

    const int start = starts[blk];
    const int end = (w == maxw) ? (S - 1) : starts[blk + 1];
    const int cnt = end - start;

    const float4* __restrict__ base = (const float4*)(hs + (size_t)b * S * H);

    float4 acc = make_float4(0.f, 0.f, 0.f, 0.f);
    for (int s = start; s < end; ++s) {
        float4 v = base[(size_t)s * VEC_PER_ROW + t];
        acc.x += v.x; acc.y += v.y; acc.z += v.z; acc.w += v.w;
    }

    const float inv = 1.0f / (float)cnt; // cnt >= 1 for existing words
    acc.x *= inv; acc.y *= inv; acc.z *= inv; acc.w *= inv;
    o[t] = acc;
}

extern "C" void kernel_launch(void* const* d_in, const int* in_sizes, int n_in,
                              void* d_out, int out_size, void* d_ws, size_t ws_size,
                              hipStream_t stream) {
    const float* hs = (const float*)d_in[0];
    const int* wid = (const int*)d_in[1];
    float* out = (float*)d_out;
    int* starts = (int*)d_ws; // B*NW ints = 128 KB scratch

    find_starts_kernel<<<(B * S) / 256, 256, 0, stream>>>(wid, starts);
    seg_mean_kernel<<<B * NW, VEC_PER_ROW, 0, stream>>>(hs, wid, starts, out);
}

// Round 3
// 330.885 us; speedup vs baseline: 1.0758x; 1.0350x over previous
//
#include <hip/hip_runtime.h>

// Problem constants (from reference): B=16, S=4096, H=768, NUM_WORDS=2048.
constexpr int B = 16;
constexpr int S = 4096;
constexpr int H = 768;
constexpr int NW = 2048;
constexpr int V4 = H / 4;          // 192 float4 per token row
constexpr int WAVES_PER_BLK = 16;  // 1024 threads = 16 waves, one word per wave

// Phase 1: word_ids[b, 1..S-2] is non-decreasing (increments 0/1), sentinels
// -1 at s=0, s=S-1. Position s starts word row[s] iff row[s] != row[s-1].
// Scatter each word's start index. Entries for non-existent words (w > maxw)
// are never written and never read (guarded by maxw in phase 2).
__global__ __launch_bounds__(256)
void find_starts_kernel(const int* __restrict__ wid, int* __restrict__ starts) {
    const int idx = blockIdx.x * 256 + threadIdx.x; // over B*S
    const int s = idx & (S - 1);
    const int b = idx >> 12;
    if (s < 1 || s >= S - 1) return;
    const int* __restrict__ row = wid + (size_t)b * S;
    const int cur = row[s];
    if (cur != row[s - 1] && cur >= 0) starts[b * NW + cur] = s;
}

// Phase 2: one WAVE per (b, word); 16 words per block. Each lane owns 3
// float4 columns (64 lanes x 3 x 4 floats = 768 = H). Tokens of word w are
// the contiguous range [starts[w], next start) — all control is wave-uniform.
__global__ __launch_bounds__(64 * WAVES_PER_BLK)
void seg_mean_kernel(const float* __restrict__ hs,
                     const int* __restrict__ wid,
                     const int* __restrict__ starts,
                     float* __restrict__ out) {
    const int wave = threadIdx.x >> 6;
    const int lane = threadIdx.x & 63;
    const int blk = blockIdx.x * WAVES_PER_BLK + wave; // b * NW + w
    const int b = blk >> 11;
    const int w = blk & (NW - 1);

    float4* __restrict__ o = (float4*)(out + (size_t)blk * H);

    const int maxw = wid[(size_t)b * S + (S - 2)]; // wave-uniform scalar load

    if (w > maxw) {
        float4 z = make_float4(0.f, 0.f, 0.f, 0.f);
        o[lane] = z; o[lane + 64] = z; o[lane + 128] = z;
        return;
    }

    const int start = starts[blk];
    const int end = (w == maxw) ? (S - 1) : starts[blk + 1];
    const int cnt = end - start;

    const float4* __restrict__ base = (const float4*)(hs + (size_t)b * S * H);

    float4 a0 = make_float4(0.f, 0.f, 0.f, 0.f);
    float4 a1 = a0, a2 = a0;

    int s = start;
    // 2-token unroll: 6 independent float4 loads in flight per lane.
    for (; s + 1 < end; s += 2) {
        const float4* p0 = base + (size_t)s * V4;
        const float4* p1 = p0 + V4;
        float4 v0 = p0[lane], v1 = p0[lane + 64], v2 = p0[lane + 128];
        float4 u0 = p1[lane], u1 = p1[lane + 64], u2 = p1[lane + 128];
        a0.x += v0.x; a0.y += v0.y; a0.z += v0.z; a0.w += v0.w;
        a1.x += v1.x; a1.y += v1.y; a1.z += v1.z; a1.w += v1.w;
        a2.x += v2.x; a2.y += v2.y; a2.z += v2.z; a2.w += v2.w;
        a0.x += u0.x; a0.y += u0.y; a0.z += u0.z; a0.w += u0.w;
        a1.x += u1.x; a1.y += u1.y; a1.z += u1.z; a1.w += u1.w;
        a2.x += u2.x; a2.y += u2.y; a2.z += u2.z; a2.w += u2.w;
    }
    if (s < end) {
        const float4* p0 = base + (size_t)s * V4;
        float4 v0 = p0[lane], v1 = p0[lane + 64], v2 = p0[lane + 128];
        a0.x += v0.x; a0.y += v0.y; a0.z += v0.z; a0.w += v0.w;
        a1.x += v1.x; a1.y += v1.y; a1.z += v1.z; a1.w += v1.w;
        a2.x += v2.x; a2.y += v2.y; a2.z += v2.z; a2.w += v2.w;
    }

    const float inv = 1.0f / (float)cnt; // cnt >= 1 for existing words
    a0.x *= inv; a0.y *= inv; a0.z *= inv; a0.w *= inv;
    a1.x *= inv; a1.y *= inv; a1.z *= inv; a1.w *= inv;
    a2.x *= inv; a2.y *= inv; a2.z *= inv; a2.w *= inv;
    o[lane] = a0; o[lane + 64] = a1; o[lane + 128] = a2;
}

extern "C" void kernel_launch(void* const* d_in, const int* in_sizes, int n_in,
                              void* d_out, int out_size, void* d_ws, size_t ws_size,
                              hipStream_t stream) {
    const float* hs = (const float*)d_in[0];
    const int* wid = (const int*)d_in[1];
    float* out = (float*)d_out;
    int* starts = (int*)d_ws; // B*NW ints = 128 KB scratch

    find_starts_kernel<<<(B * S) / 256, 256, 0, stream>>>(wid, starts);
    seg_mean_kernel<<<(B * NW) / WAVES_PER_BLK, 64 * WAVES_PER_BLK, 0, stream>>>(
        hs, wid, starts, out);
}